// Round 2
// baseline (244.492 us; speedup 1.0000x reference)
//
#include <hip/hip_runtime.h>
#include <math.h>

#define HH 128
#define WW 128
#define HWSZ (HH * WW)
#define BB 2
#define COUT 128

typedef __bf16 bf16x8 __attribute__((ext_vector_type(8)));
typedef float f32x4 __attribute__((ext_vector_type(4)));
typedef float f32x2 __attribute__((ext_vector_type(2)));
typedef short s16x8 __attribute__((ext_vector_type(8)));
typedef short s16x4 __attribute__((ext_vector_type(4)));
typedef unsigned short u16x4 __attribute__((ext_vector_type(4)));
typedef unsigned short u16x8 __attribute__((ext_vector_type(8)));

__device__ __forceinline__ short tobf(float f) {
  union { float f; unsigned u; } v; v.f = f;
  unsigned r = v.u + 0x7fffu + ((v.u >> 16) & 1u);  // RNE
  return (short)(r >> 16);
}
__device__ __forceinline__ float asf(unsigned u) {
  union { unsigned u; float f; } v; v.u = u;
  return v.f;
}
__device__ __forceinline__ f32x2 up2(unsigned u) {   // 2 bf16 -> 2 f32
  f32x2 r; r[0] = asf(u << 16); r[1] = asf(u & 0xffff0000u); return r;
}
// truncating pack of 2 f32 -> 2 bf16 in ONE v_perm_b32
__device__ __forceinline__ unsigned trunc2bf(f32x2 v) {
  union { float f; unsigned u; } a, b;
  a.f = v[0]; b.f = v[1];
  return __builtin_amdgcn_perm(b.u, a.u, 0x07060302u);
}

// ---------------------------------------------------------------------------
// Merged prep (same as rounds 9-13).
// ---------------------------------------------------------------------------
#define PA0 73728
#define PA1 221184
#define PA2 229376
#define PA3 247808
#define PA4 284672
#define PA5 284928
__global__ __launch_bounds__(256) void prep_all_kernel(
    const float* __restrict__ dc1_w, const float* __restrict__ dc2_w,
    const float* __restrict__ id_w, const float* __restrict__ dc1_offw,
    const float* __restrict__ dc2_offw,
    const float* g1, const float* b1, const float* m1, const float* v1,
    const float* g2, const float* b2, const float* m2, const float* v2,
    const float* g3, const float* b3, const float* m3, const float* v3,
    const float* idb,
    short* __restrict__ wbf1, short* __restrict__ wbf2,
    short* __restrict__ woff1, short* __restrict__ woff2,
    float* __restrict__ cb1, float* __restrict__ cb2) {
  int idx = blockIdx.x * 256 + threadIdx.x;
  if (idx < PA0) {
    int o = idx / 576, k = idx - o * 576;
    float inv = g1[o] / sqrtf(v1[o] + 1e-5f);
    int col = (k % 9) * 64 + k / 9;
    int di = (((col >> 5) * 2 + (o >> 6)) * 4 + ((o >> 4) & 3)) * 512
           + (((o & 15) | (((col >> 3) & 3) << 4)) * 8) + (col & 7);
    wbf1[di] = tobf(dc1_w[(size_t)o * 576 + k] * inv);
  } else if (idx < PA1) {
    int j = idx - PA0;
    int o = j / 1152, k = j - o * 1152;
    float inv = g2[o] / sqrtf(v2[o] + 1e-5f);
    int col = (k % 9) * 128 + k / 9;
    int di = (((col >> 5) * 2 + (o >> 6)) * 4 + ((o >> 4) & 3)) * 512
           + (((o & 15) | (((col >> 3) & 3) << 4)) * 8) + (col & 7);
    wbf2[di] = tobf(dc2_w[(size_t)o * 1152 + k] * inv);
  } else if (idx < PA2) {
    int j = idx - PA1;
    int o = j >> 6, k = j & 63;
    float inv = g3[o] / sqrtf(v3[o] + 1e-5f);
    int col = 1152 + k;
    int di = (((col >> 5) * 2 + (o >> 6)) * 4 + ((o >> 4) & 3)) * 512
           + (((o & 15) | (((col >> 3) & 3) << 4)) * 8) + (col & 7);
    wbf2[di] = tobf(id_w[(size_t)o * 64 + k] * inv);
  } else if (idx < PA3) {
    int j = idx - PA2;
    int o = j / 576, k = j - o * 576;
    int col = (k % 9) * 64 + k / 9;
    int di = ((col >> 5) * 2 + (o >> 4)) * 512 + ((col >> 3) & 3) * 128
           + (o & 15) * 8 + (col & 7);
    woff1[di] = (o < 18) ? tobf(dc1_offw[(size_t)o * 576 + k]) : (short)0;
  } else if (idx < PA4) {
    int j = idx - PA3;
    int o = j / 1152, k = j - o * 1152;
    int col = (k % 9) * 128 + k / 9;
    int di = ((col >> 5) * 2 + (o >> 4)) * 512 + ((col >> 3) & 3) * 128
           + (o & 15) * 8 + (col & 7);
    woff2[di] = (o < 18) ? tobf(dc2_offw[(size_t)o * 1152 + k]) : (short)0;
  } else if (idx < PA5) {
    int j = idx - PA4;
    if (j < 128) {
      float inv = g1[j] / sqrtf(v1[j] + 1e-5f);
      cb1[j] = b1[j] - m1[j] * inv;
    } else {
      int o = j - 128;
      float inv2_ = g2[o] / sqrtf(v2[o] + 1e-5f);
      float inv3_ = g3[o] / sqrtf(v3[o] + 1e-5f);
      cb2[o] = (b2[o] - m2[o] * inv2_) + idb[o] * inv3_ + (b3[o] - m3[o] * inv3_);
    }
  }
}

// ---------------------------------------------------------------------------
// x (B,64,H,W) fp32 NCHW -> xnhwc (B,H,W,64) bf16
// ---------------------------------------------------------------------------
__global__ __launch_bounds__(256) void xcast_kernel(const float* __restrict__ x,
                                                    unsigned short* __restrict__ xn) {
  __shared__ short lds[64 * 72];
  int tid = threadIdx.x;
  int gp0 = blockIdx.x * 64;
  int b = gp0 >> 14;
  int pl0 = gp0 & 16383;
  int p = tid & 63;
  int cb = (tid >> 6) * 16;
#pragma unroll
  for (int i = 0; i < 16; i++) {
    int c = cb + i;
    lds[p * 72 + c] = tobf(x[((size_t)(b * 64 + c)) * HWSZ + pl0 + p]);
  }
  __syncthreads();
  int pw = tid >> 2, cseg = (tid & 3) * 16;
  u16x8 a = *(const u16x8*)&lds[pw * 72 + cseg];
  u16x8 b8 = *(const u16x8*)&lds[pw * 72 + cseg + 8];
  *(u16x8*)&xn[(size_t)(gp0 + pw) * 64 + cseg] = a;
  *(u16x8*)&xn[(size_t)(gp0 + pw) * 64 + cseg + 8] = b8;
}

// ---------------------------------------------------------------------------
// FUSED layer kernel.  Phase C now runs a DEPTH-2 gather pipeline:
// three rotating q-register sets (A,B,C) so chunk i's scattered bilinear
// gathers are issued ~2 COMPUTEs (~1000 cyc) before their blend consumes
// them (latency-bound fix: MfmaUtil 9.5%/VALUBusy 25% at depth-1).
// Weights use a single register set reloaded per chunk (L2-hot, hides
// under the next blend).  s_setprio(1) wraps the MFMA cluster (T5).
// ---------------------------------------------------------------------------
#define LOADW1(kc_)                                             \
  {                                                             \
    const short* wf_ = wfb + (size_t)(kc_) * 4096;              \
    w0 = *(const bf16x8*)(wf_);                                 \
    w1 = *(const bf16x8*)(wf_ + 512);                           \
    w2 = *(const bf16x8*)(wf_ + 1024);                          \
    w3 = *(const bf16x8*)(wf_ + 1536);                          \
    w4 = *(const bf16x8*)(wf_ + 2048);                          \
    w5 = *(const bf16x8*)(wf_ + 2560);                          \
    w6 = *(const bf16x8*)(wf_ + 3072);                          \
    w7 = *(const bf16x8*)(wf_ + 3584);                          \
  }

#define LOADT(P, kc_)                                           \
  {                                                             \
    int k0_ = (kc_) << 5;                                       \
    int n_ = k0_ >> CSH;                                        \
    int c0_ = (k0_ & (Cin - 1)) + cq * 8;                       \
    uint4 d4_ = dsu[(n_ << 6) + dp0];                           \
    int dx_ = (int)(d4_.w & 0xffffu);                           \
    int dy_ = (int)d4_.w >> 16;                                 \
    const unsigned short* p_ = inb + (int)d4_.z + c0_;          \
    P##q00 = *(const uint4*)(p_);                               \
    P##q01 = *(const uint4*)(p_ + dx_);                         \
    P##q02 = *(const uint4*)(p_ + dy_);                         \
    P##q03 = *(const uint4*)(p_ + dx_ + dy_);                   \
    P##wa0 = d4_.x; P##wb0 = d4_.y;                             \
    uint4 e4_ = dsu[(n_ << 6) + dp1];                           \
    int ex_ = (int)(e4_.w & 0xffffu);                           \
    int ey_ = (int)e4_.w >> 16;                                 \
    const unsigned short* q_ = inb + (int)e4_.z + c0_;          \
    P##q10 = *(const uint4*)(q_);                               \
    P##q11 = *(const uint4*)(q_ + ex_);                         \
    P##q12 = *(const uint4*)(q_ + ey_);                         \
    P##q13 = *(const uint4*)(q_ + ex_ + ey_);                   \
    P##wa1 = e4_.x; P##wb1 = e4_.y;                             \
  }

// explicit-register blend (no pasting adjacent to member access)
#define BLEND1(r0, r1, r2, r3, wav, wbv, pkv)                                 \
  {                                                                           \
    float w0_ = asf((wav) << 16), w1_ = asf((wav) & 0xffff0000u);             \
    float w2_ = asf((wbv) << 16), w3_ = asf((wbv) & 0xffff0000u);             \
    f32x2 v0_ = up2(r0.x) * w0_ + up2(r1.x) * w1_                             \
              + up2(r2.x) * w2_ + up2(r3.x) * w3_;                            \
    f32x2 v1_ = up2(r0.y) * w0_ + up2(r1.y) * w1_                             \
              + up2(r2.y) * w2_ + up2(r3.y) * w3_;                            \
    f32x2 v2_ = up2(r0.z) * w0_ + up2(r1.z) * w1_                             \
              + up2(r2.z) * w2_ + up2(r3.z) * w3_;                            \
    f32x2 v3_ = up2(r0.w) * w0_ + up2(r1.w) * w1_                             \
              + up2(r2.w) * w2_ + up2(r3.w) * w3_;                            \
    pkv.x = trunc2bf(v0_); pkv.y = trunc2bf(v1_);                             \
    pkv.z = trunc2bf(v2_); pkv.w = trunc2bf(v3_);                             \
  }

#define XPOSE(pkv, bfrv)                                                      \
  {                                                                           \
    union { int i[4]; bf16x8 v; } bu_;                                        \
    bu_.i[0] = __builtin_amdgcn_ds_bpermute(baddr, (int)pkv.x);               \
    bu_.i[1] = __builtin_amdgcn_ds_bpermute(baddr, (int)pkv.y);               \
    bu_.i[2] = __builtin_amdgcn_ds_bpermute(baddr, (int)pkv.z);               \
    bu_.i[3] = __builtin_amdgcn_ds_bpermute(baddr, (int)pkv.w);               \
    bfrv = bu_.v;                                                             \
  }

#define MFMA16(bfr0v, bfr1v)                                                        \
  {                                                                                 \
    acc[0] = __builtin_amdgcn_mfma_f32_16x16x32_bf16(w0, bfr0v, acc[0], 0, 0, 0);   \
    acc[8] = __builtin_amdgcn_mfma_f32_16x16x32_bf16(w0, bfr1v, acc[8], 0, 0, 0);   \
    acc[1] = __builtin_amdgcn_mfma_f32_16x16x32_bf16(w1, bfr0v, acc[1], 0, 0, 0);   \
    acc[9] = __builtin_amdgcn_mfma_f32_16x16x32_bf16(w1, bfr1v, acc[9], 0, 0, 0);   \
    acc[2] = __builtin_amdgcn_mfma_f32_16x16x32_bf16(w2, bfr0v, acc[2], 0, 0, 0);   \
    acc[10] = __builtin_amdgcn_mfma_f32_16x16x32_bf16(w2, bfr1v, acc[10], 0, 0, 0); \
    acc[3] = __builtin_amdgcn_mfma_f32_16x16x32_bf16(w3, bfr0v, acc[3], 0, 0, 0);   \
    acc[11] = __builtin_amdgcn_mfma_f32_16x16x32_bf16(w3, bfr1v, acc[11], 0, 0, 0); \
    acc[4] = __builtin_amdgcn_mfma_f32_16x16x32_bf16(w4, bfr0v, acc[4], 0, 0, 0);   \
    acc[12] = __builtin_amdgcn_mfma_f32_16x16x32_bf16(w4, bfr1v, acc[12], 0, 0, 0); \
    acc[5] = __builtin_amdgcn_mfma_f32_16x16x32_bf16(w5, bfr0v, acc[5], 0, 0, 0);   \
    acc[13] = __builtin_amdgcn_mfma_f32_16x16x32_bf16(w5, bfr1v, acc[13], 0, 0, 0); \
    acc[6] = __builtin_amdgcn_mfma_f32_16x16x32_bf16(w6, bfr0v, acc[6], 0, 0, 0);   \
    acc[14] = __builtin_amdgcn_mfma_f32_16x16x32_bf16(w6, bfr1v, acc[14], 0, 0, 0); \
    acc[7] = __builtin_amdgcn_mfma_f32_16x16x32_bf16(w7, bfr0v, acc[7], 0, 0, 0);   \
    acc[15] = __builtin_amdgcn_mfma_f32_16x16x32_bf16(w7, bfr1v, acc[15], 0, 0, 0); \
  }

#define COMPUTEB(P)                                                           \
  {                                                                           \
    uint4 pk0_, pk1_;                                                         \
    BLEND1(P##q00, P##q01, P##q02, P##q03, P##wa0, P##wb0, pk0_);             \
    BLEND1(P##q10, P##q11, P##q12, P##q13, P##wa1, P##wb1, pk1_);             \
    bf16x8 bf0_, bf1_;                                                        \
    XPOSE(pk0_, bf0_);                                                        \
    XPOSE(pk1_, bf1_);                                                        \
    __builtin_amdgcn_s_setprio(1);                                            \
    MFMA16(bf0_, bf1_);                                                       \
    __builtin_amdgcn_s_setprio(0);                                            \
  }

// one pipeline step: prefetch chunk i+2 into NX2's q-set, consume CUR
// (chunk i), then load weights for chunk i+1.  sched_barrier pins the
// prefetch above the blend against pressure-driven sinking.
#define STEP(CUR, NX2)                                                        \
  {                                                                           \
    if (i + 2 < kcEndConv) { LOADT(NX2, i + 2); }                             \
    __builtin_amdgcn_sched_barrier(0);                                        \
    COMPUTEB(CUR);                                                            \
    ++i;                                                                      \
    if (i < kcEndConv) LOADW1(i);                                             \
  }

template <int CSH, int KCONV, int KTOT, int MODE>
__global__ __launch_bounds__(256, 2) void fused_layer_kernel(
    const unsigned short* __restrict__ in, const short* __restrict__ woff,
    const float* __restrict__ offb,
    const short* __restrict__ wbf, const float* __restrict__ cbv,
    const unsigned short* __restrict__ xid, float* __restrict__ outf,
    unsigned short* __restrict__ outb) {
  __shared__ __align__(16) char smem[50176];
  uint4* dsu = (uint4*)smem;                    // [576] descriptors
  f32x4* redf = (f32x4*)smem;                   // [16*128] overlays dsu (post)
  float* offlds = (float*)(smem + 32768);       // [18*64] phase A -> B
  short* trans = (short*)(smem + 32768);        // 64 x 136 (epilogue, mode 0)

  const int tid = threadIdx.x;
  const int lane = tid & 63, wv = tid >> 6;
  const int pb = ((blockIdx.x & 7) << 6) | (blockIdx.x >> 3);  // XCD swizzle
  const int pix0 = pb << 6;
  const int x0 = pix0 & 127, y = (pix0 >> 7) & 127, b = pix0 >> 14;
  constexpr int Cin = 1 << CSH;
  const unsigned short* inb = in + (size_t)b * HWSZ * Cin;
  const int l15 = lane & 15, quad = lane >> 4;
  const int pxg = wv & 1, kh = wv >> 1;         // phase-C wave roles
  const int dp0 = pxg * 32 + (lane >> 2);
  const int dp1 = dp0 + 16;
  const int cq = lane & 3;
  const int baddr = (((lane & 15) << 2) | (lane >> 4)) << 2;  // bpermute src*4

  // ================= Phase A: offset conv (16 px x 32 M per wave) ========
  {
    constexpr int NCh = (9 << CSH) >> 5;        // 18 or 36
    const int pxa = wv;                          // wave = px group 0..3
    const int px = x0 + pxa * 16 + l15;
    f32x4 aco0 = {0.f, 0.f, 0.f, 0.f};
    f32x4 aco1 = {0.f, 0.f, 0.f, 0.f};
#pragma unroll
    for (int i = 0; i < NCh; i++) {
      int k0 = i * 32;
      int n = k0 >> CSH;
      int c0 = (k0 & (Cin - 1)) + quad * 8;
      int yy = y + n / 3 - 1;
      int xx = px + n % 3 - 1;
      bf16x8 bv = {};
      if (((unsigned)yy < (unsigned)HH) && ((unsigned)xx < (unsigned)WW))
        bv = *(const bf16x8*)&inb[((size_t)yy * WW + xx) * Cin + c0];
      int fbase = i * 1024 + lane * 8;
      bf16x8 a0 = *(const bf16x8*)&woff[fbase];
      bf16x8 a1 = *(const bf16x8*)&woff[fbase + 512];
      aco0 = __builtin_amdgcn_mfma_f32_16x16x32_bf16(a0, bv, aco0, 0, 0, 0);
      aco1 = __builtin_amdgcn_mfma_f32_16x16x32_bf16(a1, bv, aco1, 0, 0, 0);
    }
#pragma unroll
    for (int r = 0; r < 4; r++) {
      int o0 = quad * 4 + r;                     // 0..15: always valid
      offlds[o0 * 64 + pxa * 16 + l15] = aco0[r] + offb[o0];
      int o1 = 16 + quad * 4 + r;
      if (o1 < 18)
        offlds[o1 * 64 + pxa * 16 + l15] = aco1[r] + offb[o1];
    }
  }

  // pipeline register sets (named; no runtime-indexed arrays -> no scratch)
  bf16x8 w0, w1, w2, w3, w4, w5, w6, w7;        // single weight set
  uint4 Aq00, Aq01, Aq02, Aq03, Aq10, Aq11, Aq12, Aq13;
  uint4 Bq00, Bq01, Bq02, Bq03, Bq10, Bq11, Bq12, Bq13;
  uint4 Cq00, Cq01, Cq02, Cq03, Cq10, Cq11, Cq12, Cq13;
  unsigned Awa0, Awb0, Awa1, Awb1;
  unsigned Bwa0, Bwb0, Bwa1, Bwb1;
  unsigned Cwa0, Cwb0, Cwa1, Cwb1;

  constexpr int NC = KTOT >> 5;
  constexpr int NCONV = KCONV >> 5;
  constexpr int HC = NC >> 1;
  const int kcBeg = kh * HC;
  const int kcEnd = kcBeg + HC;
  const int kcEndConv = (kcEnd < NCONV) ? kcEnd : NCONV;
  const short* wfb = wbf + lane * 8;

  LOADW1(kcBeg);              // weights don't depend on descriptors
  __syncthreads();            // offlds complete

  // ================= Phase B: bilinear descriptors ========================
  for (int t = tid; t < 576; t += 256) {
    int n = t >> 6, pp = t & 63;
    float offy = offlds[n * 64 + pp];
    float offx = offlds[(9 + n) * 64 + pp];
    float py = offy + (float)(n / 3 - 1) + (float)(y + 1);
    float px = offx + (float)(n % 3 - 1) + (float)(x0 + pp + 1);
    py = fminf(fmaxf(py, 0.f), 129.f);
    px = fminf(fmaxf(px, 0.f), 129.f);
    float fy = floorf(py), fx = floorf(px);
    float qy1 = fminf(fy + 1.f, 129.f), qx1 = fminf(fx + 1.f, 129.f);
    float ty0 = 1.f + fy - py, ty1 = 1.f - (qy1 - py);
    float tx0 = 1.f + fx - px, tx1 = 1.f - (qx1 - px);
    int iy0 = (int)fy - 1, ix0 = (int)fx - 1;
    int iy1 = (int)qy1 - 1, ix1 = (int)qx1 - 1;
    if ((unsigned)iy0 >= (unsigned)HH) ty0 = 0.f;
    if ((unsigned)iy1 >= (unsigned)HH) ty1 = 0.f;
    if ((unsigned)ix0 >= (unsigned)WW) tx0 = 0.f;
    if ((unsigned)ix1 >= (unsigned)WW) tx1 = 0.f;
    int by0 = min(max(iy0, 0), HH - 1), by1 = min(max(iy1, 0), HH - 1);
    int bx0 = min(max(ix0, 0), WW - 1), bx1 = min(max(ix1, 0), WW - 1);
    uint4 d4;
    d4.x = (unsigned)(unsigned short)tobf(ty0 * tx0)
         | ((unsigned)(unsigned short)tobf(ty0 * tx1) << 16);
    d4.y = (unsigned)(unsigned short)tobf(ty1 * tx0)
         | ((unsigned)(unsigned short)tobf(ty1 * tx1) << 16);
    d4.z = (unsigned)((by0 * WW + bx0) * Cin);
    d4.w = (unsigned)((((by1 - by0) * WW * Cin) << 16) | ((bx1 - bx0) * Cin));
    dsu[t] = d4;
  }

  f32x4 acc[16];
#pragma unroll
  for (int j = 0; j < 16; j++) acc[j] = (f32x4){0.f, 0.f, 0.f, 0.f};

  __syncthreads();            // descriptors ready

  // ================= Phase C: depth-2 pipelined deform GEMM ===============
  int i = kcBeg;
  if (i < kcEndConv) {
    LOADT(A, i);
    if (i + 1 < kcEndConv) LOADT(B, i + 1);
    while (true) {
      STEP(A, C);
      if (i >= kcEndConv) break;
      STEP(B, A);
      if (i >= kcEndConv) break;
      STEP(C, B);
      if (i >= kcEndConv) break;
    }
  }

  // residual (identity) chunks: layer 2, kh=1 only
  if (KCONV < KTOT) {
    for (; i < kcEnd; i++) {
      LOADW1(i);
      int c = ((i << 5) - KCONV) + cq * 8;
      uint4 pk0 = *(const uint4*)&xid[((size_t)(b * HWSZ) + y * WW + x0 + dp0) * 64 + c];
      uint4 pk1 = *(const uint4*)&xid[((size_t)(b * HWSZ) + y * WW + x0 + dp1) * 64 + c];
      bf16x8 bf0, bf1;
      XPOSE(pk0, bf0);
      XPOSE(pk1, bf1);
      __builtin_amdgcn_s_setprio(1);
      MFMA16(bf0, bf1);
      __builtin_amdgcn_s_setprio(0);
    }
  }

  // ---- K-half reduce (redf overlays dsu; both dead regions by now) ----
  __syncthreads();
  if (kh == 1) {
#pragma unroll
    for (int f = 0; f < 16; f++) redf[f * 128 + pxg * 64 + lane] = acc[f];
  }
  __syncthreads();
  if (kh == 0) {
#pragma unroll
    for (int f = 0; f < 16; f++) acc[f] += redf[f * 128 + pxg * 64 + lane];
    if (MODE == 1) {
#pragma unroll
      for (int f = 0; f < 16; f++) {
        int px_ = x0 + pxg * 32 + (f >> 3) * 16 + l15;
        int fo = f & 7;
#pragma unroll
        for (int r = 0; r < 4; r++) {
          int o = (fo >> 2) * 64 + (fo & 3) * 16 + quad * 4 + r;
          outf[(size_t)(b * COUT + o) * HWSZ + y * WW + px_] =
              fmaxf(acc[f][r] + cbv[o], 0.f);
        }
      }
    } else {
#pragma unroll
      for (int f = 0; f < 16; f++) {
        int pl = pxg * 32 + (f >> 3) * 16 + l15;
        int fo = f & 7;
        s16x4 t4;
#pragma unroll
        for (int r = 0; r < 4; r++) {
          int o = (fo >> 2) * 64 + (fo & 3) * 16 + quad * 4 + r;
          t4[r] = tobf(fmaxf(acc[f][r] + cbv[o], 0.f));
        }
        *(s16x4*)&trans[pl * 136 + (fo >> 2) * 64 + (fo & 3) * 16 + quad * 4] = t4;
      }
    }
  }
  if (MODE == 0) {
    __syncthreads();
    int pw = tid >> 2, cs = (tid & 3) * 32;
    size_t gb = ((size_t)(b * HWSZ) + y * WW + x0 + pw) * 128 + cs;
#pragma unroll
    for (int s = 0; s < 4; s++) {
      u16x8 v8 = *(const u16x8*)&trans[pw * 136 + cs + s * 8];
      *(u16x8*)&outb[gb + s * 8] = v8;
    }
  }
}

// ---------------------------------------------------------------------------
extern "C" void kernel_launch(void* const* d_in, const int* in_sizes, int n_in,
                              void* d_out, int out_size, void* d_ws, size_t ws_size,
                              hipStream_t stream) {
  const float* x        = (const float*)d_in[0];
  const float* dc1_offw = (const float*)d_in[1];
  const float* dc1_offb = (const float*)d_in[2];
  const float* dc1_w    = (const float*)d_in[3];
  const float* bn1_g    = (const float*)d_in[4];
  const float* bn1_b    = (const float*)d_in[5];
  const float* bn1_m    = (const float*)d_in[6];
  const float* bn1_v    = (const float*)d_in[7];
  const float* dc2_offw = (const float*)d_in[8];
  const float* dc2_offb = (const float*)d_in[9];
  const float* dc2_w    = (const float*)d_in[10];
  const float* bn2_g    = (const float*)d_in[11];
  const float* bn2_b    = (const float*)d_in[12];
  const float* bn2_m    = (const float*)d_in[13];
  const float* bn2_v    = (const float*)d_in[14];
  const float* id_w     = (const float*)d_in[15];
  const float* id_b     = (const float*)d_in[16];
  const float* bn3_g    = (const float*)d_in[17];
  const float* bn3_b    = (const float*)d_in[18];
  const float* bn3_m    = (const float*)d_in[19];
  const float* bn3_v    = (const float*)d_in[20];

  float* wsf = (float*)d_ws;
  float* cb1  = wsf;
  float* cb2  = cb1 + 128;
  unsigned short* xbf = (unsigned short*)(cb2 + 128);  // NHWC (B,H,W,64)
  unsigned short* h1  = xbf + (size_t)BB * HWSZ * 64;  // NHWC (B,H,W,128)
  short* wbf1  = (short*)(h1 + (size_t)BB * HWSZ * COUT);  // frag 128x576
  short* wbf2  = wbf1 + (size_t)128 * 576;             // frag 128x1216
  short* woff1 = wbf2 + (size_t)128 * 1216;            // frag-order 18*1024
  short* woff2 = woff1 + (size_t)18 * 1024;            // frag-order 36*1024

  hipLaunchKernelGGL(prep_all_kernel, dim3((PA5 + 255) / 256), dim3(256), 0, stream,
                     dc1_w, dc2_w, id_w, dc1_offw, dc2_offw,
                     bn1_g, bn1_b, bn1_m, bn1_v, bn2_g, bn2_b, bn2_m, bn2_v,
                     bn3_g, bn3_b, bn3_m, bn3_v, id_b,
                     wbf1, wbf2, woff1, woff2, cb1, cb2);
  hipLaunchKernelGGL(xcast_kernel, dim3(BB * HWSZ / 64), dim3(256), 0, stream, x, xbf);

  // --- layer 1 (offset conv fused) ---
  hipLaunchKernelGGL((fused_layer_kernel<6, 576, 576, 0>), dim3(512), dim3(256), 0, stream,
                     xbf, woff1, dc1_offb, wbf1, cb1,
                     (const unsigned short*)nullptr, (float*)nullptr, h1);
  // --- layer 2 (offset conv + identity residual fused) ---
  hipLaunchKernelGGL((fused_layer_kernel<7, 1152, 1216, 1>), dim3(512), dim3(256), 0, stream,
                     h1, woff2, dc2_offb, wbf2, cb2,
                     xbf, (float*)d_out, (unsigned short*)nullptr);
}

// Round 3
// 171.365 us; speedup vs baseline: 1.4267x; 1.4267x over previous
//
#include <hip/hip_runtime.h>
#include <math.h>

#define HH 128
#define WW 128
#define HWSZ (HH * WW)
#define BB 2
#define COUT 128

typedef __bf16 bf16x8 __attribute__((ext_vector_type(8)));
typedef float f32x4 __attribute__((ext_vector_type(4)));
typedef float f32x2 __attribute__((ext_vector_type(2)));
typedef short s16x8 __attribute__((ext_vector_type(8)));
typedef short s16x4 __attribute__((ext_vector_type(4)));
typedef unsigned short u16x4 __attribute__((ext_vector_type(4)));
typedef unsigned short u16x8 __attribute__((ext_vector_type(8)));

__device__ __forceinline__ short tobf(float f) {
  union { float f; unsigned u; } v; v.f = f;
  unsigned r = v.u + 0x7fffu + ((v.u >> 16) & 1u);  // RNE
  return (short)(r >> 16);
}
__device__ __forceinline__ float asf(unsigned u) {
  union { unsigned u; float f; } v; v.u = u;
  return v.f;
}
__device__ __forceinline__ f32x2 up2(unsigned u) {   // 2 bf16 -> 2 f32
  f32x2 r; r[0] = asf(u << 16); r[1] = asf(u & 0xffff0000u); return r;
}
// truncating pack of 2 f32 -> 2 bf16 in ONE v_perm_b32
__device__ __forceinline__ unsigned trunc2bf(f32x2 v) {
  union { float f; unsigned u; } a, b;
  a.f = v[0]; b.f = v[1];
  return __builtin_amdgcn_perm(b.u, a.u, 0x07060302u);
}

// ---------------------------------------------------------------------------
// Merged prep (same as rounds 9-13).
// ---------------------------------------------------------------------------
#define PA0 73728
#define PA1 221184
#define PA2 229376
#define PA3 247808
#define PA4 284672
#define PA5 284928
__global__ __launch_bounds__(256) void prep_all_kernel(
    const float* __restrict__ dc1_w, const float* __restrict__ dc2_w,
    const float* __restrict__ id_w, const float* __restrict__ dc1_offw,
    const float* __restrict__ dc2_offw,
    const float* g1, const float* b1, const float* m1, const float* v1,
    const float* g2, const float* b2, const float* m2, const float* v2,
    const float* g3, const float* b3, const float* m3, const float* v3,
    const float* idb,
    short* __restrict__ wbf1, short* __restrict__ wbf2,
    short* __restrict__ woff1, short* __restrict__ woff2,
    float* __restrict__ cb1, float* __restrict__ cb2) {
  int idx = blockIdx.x * 256 + threadIdx.x;
  if (idx < PA0) {
    int o = idx / 576, k = idx - o * 576;
    float inv = g1[o] / sqrtf(v1[o] + 1e-5f);
    int col = (k % 9) * 64 + k / 9;
    int di = (((col >> 5) * 2 + (o >> 6)) * 4 + ((o >> 4) & 3)) * 512
           + (((o & 15) | (((col >> 3) & 3) << 4)) * 8) + (col & 7);
    wbf1[di] = tobf(dc1_w[(size_t)o * 576 + k] * inv);
  } else if (idx < PA1) {
    int j = idx - PA0;
    int o = j / 1152, k = j - o * 1152;
    float inv = g2[o] / sqrtf(v2[o] + 1e-5f);
    int col = (k % 9) * 128 + k / 9;
    int di = (((col >> 5) * 2 + (o >> 6)) * 4 + ((o >> 4) & 3)) * 512
           + (((o & 15) | (((col >> 3) & 3) << 4)) * 8) + (col & 7);
    wbf2[di] = tobf(dc2_w[(size_t)o * 1152 + k] * inv);
  } else if (idx < PA2) {
    int j = idx - PA1;
    int o = j >> 6, k = j & 63;
    float inv = g3[o] / sqrtf(v3[o] + 1e-5f);
    int col = 1152 + k;
    int di = (((col >> 5) * 2 + (o >> 6)) * 4 + ((o >> 4) & 3)) * 512
           + (((o & 15) | (((col >> 3) & 3) << 4)) * 8) + (col & 7);
    wbf2[di] = tobf(id_w[(size_t)o * 64 + k] * inv);
  } else if (idx < PA3) {
    int j = idx - PA2;
    int o = j / 576, k = j - o * 576;
    int col = (k % 9) * 64 + k / 9;
    int di = ((col >> 5) * 2 + (o >> 4)) * 512 + ((col >> 3) & 3) * 128
           + (o & 15) * 8 + (col & 7);
    woff1[di] = (o < 18) ? tobf(dc1_offw[(size_t)o * 576 + k]) : (short)0;
  } else if (idx < PA4) {
    int j = idx - PA3;
    int o = j / 1152, k = j - o * 1152;
    int col = (k % 9) * 128 + k / 9;
    int di = ((col >> 5) * 2 + (o >> 4)) * 512 + ((col >> 3) & 3) * 128
           + (o & 15) * 8 + (col & 7);
    woff2[di] = (o < 18) ? tobf(dc2_offw[(size_t)o * 1152 + k]) : (short)0;
  } else if (idx < PA5) {
    int j = idx - PA4;
    if (j < 128) {
      float inv = g1[j] / sqrtf(v1[j] + 1e-5f);
      cb1[j] = b1[j] - m1[j] * inv;
    } else {
      int o = j - 128;
      float inv2_ = g2[o] / sqrtf(v2[o] + 1e-5f);
      float inv3_ = g3[o] / sqrtf(v3[o] + 1e-5f);
      cb2[o] = (b2[o] - m2[o] * inv2_) + idb[o] * inv3_ + (b3[o] - m3[o] * inv3_);
    }
  }
}

// ---------------------------------------------------------------------------
// x (B,64,H,W) fp32 NCHW -> xnhwc (B,H,W,64) bf16
// ---------------------------------------------------------------------------
__global__ __launch_bounds__(256) void xcast_kernel(const float* __restrict__ x,
                                                    unsigned short* __restrict__ xn) {
  __shared__ short lds[64 * 72];
  int tid = threadIdx.x;
  int gp0 = blockIdx.x * 64;
  int b = gp0 >> 14;
  int pl0 = gp0 & 16383;
  int p = tid & 63;
  int cb = (tid >> 6) * 16;
#pragma unroll
  for (int i = 0; i < 16; i++) {
    int c = cb + i;
    lds[p * 72 + c] = tobf(x[((size_t)(b * 64 + c)) * HWSZ + pl0 + p]);
  }
  __syncthreads();
  int pw = tid >> 2, cseg = (tid & 3) * 16;
  u16x8 a = *(const u16x8*)&lds[pw * 72 + cseg];
  u16x8 b8 = *(const u16x8*)&lds[pw * 72 + cseg + 8];
  *(u16x8*)&xn[(size_t)(gp0 + pw) * 64 + cseg] = a;
  *(u16x8*)&xn[(size_t)(gp0 + pw) * 64 + cseg + 8] = b8;
}

// ---------------------------------------------------------------------------
// FUSED layer kernel: round-1 structure (depth-1 A/B ping-pong, two weight
// sets) + two low-pressure latency fixes:
//  (a) LOADT split into LOADD (descriptor LDS read -> 2 named uint4 regs,
//      issued one chunk early, hidden under COMPUTE) + LOADG (gathers
//      issue immediately from resident descriptors) -- removes the ~120cy
//      LDS latency from the head of each chunk's dependence chain.
//  (b) s_setprio(1/0) around the MFMA cluster (T5; waves drift freely).
// ---------------------------------------------------------------------------
#define LOADW(P, kc_)                                           \
  {                                                             \
    const short* wf_ = wfb + (size_t)(kc_) * 4096;              \
    P##w0 = *(const bf16x8*)(wf_);                              \
    P##w1 = *(const bf16x8*)(wf_ + 512);                        \
    P##w2 = *(const bf16x8*)(wf_ + 1024);                       \
    P##w3 = *(const bf16x8*)(wf_ + 1536);                       \
    P##w4 = *(const bf16x8*)(wf_ + 2048);                       \
    P##w5 = *(const bf16x8*)(wf_ + 2560);                       \
    P##w6 = *(const bf16x8*)(wf_ + 3072);                       \
    P##w7 = *(const bf16x8*)(wf_ + 3584);                       \
  }

// descriptor prefetch for chunk kc_ into Dd0/Dd1 (named regs)
#define LOADD(kc_)                                              \
  {                                                             \
    int n_ = ((kc_) << 5) >> CSH;                               \
    Dd0 = dsu[(n_ << 6) + dp0];                                 \
    Dd1 = dsu[(n_ << 6) + dp1];                                 \
  }

// gathers for chunk kc_ using resident Dd0/Dd1
#define LOADG(P, kc_)                                           \
  {                                                             \
    int k0_ = (kc_) << 5;                                       \
    int c0_ = (k0_ & (Cin - 1)) + cq * 8;                       \
    int dx_ = (int)(Dd0.w & 0xffffu);                           \
    int dy_ = (int)Dd0.w >> 16;                                 \
    const unsigned short* p_ = inb + (int)Dd0.z + c0_;          \
    P##q00 = *(const uint4*)(p_);                               \
    P##q01 = *(const uint4*)(p_ + dx_);                         \
    P##q02 = *(const uint4*)(p_ + dy_);                         \
    P##q03 = *(const uint4*)(p_ + dx_ + dy_);                   \
    P##wa0 = Dd0.x; P##wb0 = Dd0.y;                             \
    int ex_ = (int)(Dd1.w & 0xffffu);                           \
    int ey_ = (int)Dd1.w >> 16;                                 \
    const unsigned short* q_ = inb + (int)Dd1.z + c0_;          \
    P##q10 = *(const uint4*)(q_);                               \
    P##q11 = *(const uint4*)(q_ + ex_);                         \
    P##q12 = *(const uint4*)(q_ + ey_);                         \
    P##q13 = *(const uint4*)(q_ + ex_ + ey_);                   \
    P##wa1 = Dd1.x; P##wb1 = Dd1.y;                             \
  }

// explicit-register blend (no pasting adjacent to member access)
#define BLEND1(r0, r1, r2, r3, wav, wbv, pkv)                                 \
  {                                                                           \
    float w0_ = asf((wav) << 16), w1_ = asf((wav) & 0xffff0000u);             \
    float w2_ = asf((wbv) << 16), w3_ = asf((wbv) & 0xffff0000u);             \
    f32x2 v0_ = up2(r0.x) * w0_ + up2(r1.x) * w1_                             \
              + up2(r2.x) * w2_ + up2(r3.x) * w3_;                            \
    f32x2 v1_ = up2(r0.y) * w0_ + up2(r1.y) * w1_                             \
              + up2(r2.y) * w2_ + up2(r3.y) * w3_;                            \
    f32x2 v2_ = up2(r0.z) * w0_ + up2(r1.z) * w1_                             \
              + up2(r2.z) * w2_ + up2(r3.z) * w3_;                            \
    f32x2 v3_ = up2(r0.w) * w0_ + up2(r1.w) * w1_                             \
              + up2(r2.w) * w2_ + up2(r3.w) * w3_;                            \
    pkv.x = trunc2bf(v0_); pkv.y = trunc2bf(v1_);                             \
    pkv.z = trunc2bf(v2_); pkv.w = trunc2bf(v3_);                             \
  }

#define XPOSE(pkv, bfrv)                                                      \
  {                                                                           \
    union { int i[4]; bf16x8 v; } bu_;                                        \
    bu_.i[0] = __builtin_amdgcn_ds_bpermute(baddr, (int)pkv.x);               \
    bu_.i[1] = __builtin_amdgcn_ds_bpermute(baddr, (int)pkv.y);               \
    bu_.i[2] = __builtin_amdgcn_ds_bpermute(baddr, (int)pkv.z);               \
    bu_.i[3] = __builtin_amdgcn_ds_bpermute(baddr, (int)pkv.w);               \
    bfrv = bu_.v;                                                             \
  }

#define MFMA16(P, bfr0v, bfr1v)                                                     \
  {                                                                                 \
    acc[0] = __builtin_amdgcn_mfma_f32_16x16x32_bf16(P##w0, bfr0v, acc[0], 0, 0, 0);  \
    acc[8] = __builtin_amdgcn_mfma_f32_16x16x32_bf16(P##w0, bfr1v, acc[8], 0, 0, 0);  \
    acc[1] = __builtin_amdgcn_mfma_f32_16x16x32_bf16(P##w1, bfr0v, acc[1], 0, 0, 0);  \
    acc[9] = __builtin_amdgcn_mfma_f32_16x16x32_bf16(P##w1, bfr1v, acc[9], 0, 0, 0);  \
    acc[2] = __builtin_amdgcn_mfma_f32_16x16x32_bf16(P##w2, bfr0v, acc[2], 0, 0, 0);  \
    acc[10] = __builtin_amdgcn_mfma_f32_16x16x32_bf16(P##w2, bfr1v, acc[10], 0, 0, 0);\
    acc[3] = __builtin_amdgcn_mfma_f32_16x16x32_bf16(P##w3, bfr0v, acc[3], 0, 0, 0);  \
    acc[11] = __builtin_amdgcn_mfma_f32_16x16x32_bf16(P##w3, bfr1v, acc[11], 0, 0, 0);\
    acc[4] = __builtin_amdgcn_mfma_f32_16x16x32_bf16(P##w4, bfr0v, acc[4], 0, 0, 0);  \
    acc[12] = __builtin_amdgcn_mfma_f32_16x16x32_bf16(P##w4, bfr1v, acc[12], 0, 0, 0);\
    acc[5] = __builtin_amdgcn_mfma_f32_16x16x32_bf16(P##w5, bfr0v, acc[5], 0, 0, 0);  \
    acc[13] = __builtin_amdgcn_mfma_f32_16x16x32_bf16(P##w5, bfr1v, acc[13], 0, 0, 0);\
    acc[6] = __builtin_amdgcn_mfma_f32_16x16x32_bf16(P##w6, bfr0v, acc[6], 0, 0, 0);  \
    acc[14] = __builtin_amdgcn_mfma_f32_16x16x32_bf16(P##w6, bfr1v, acc[14], 0, 0, 0);\
    acc[7] = __builtin_amdgcn_mfma_f32_16x16x32_bf16(P##w7, bfr0v, acc[7], 0, 0, 0);  \
    acc[15] = __builtin_amdgcn_mfma_f32_16x16x32_bf16(P##w7, bfr1v, acc[15], 0, 0, 0);\
  }

#define COMPUTE(P)                                                            \
  {                                                                           \
    uint4 pk0_, pk1_;                                                         \
    BLEND1(P##q00, P##q01, P##q02, P##q03, P##wa0, P##wb0, pk0_);             \
    BLEND1(P##q10, P##q11, P##q12, P##q13, P##wa1, P##wb1, pk1_);             \
    bf16x8 bf0_, bf1_;                                                        \
    XPOSE(pk0_, bf0_);                                                        \
    XPOSE(pk1_, bf1_);                                                        \
    __builtin_amdgcn_s_setprio(1);                                            \
    MFMA16(P, bf0_, bf1_);                                                    \
    __builtin_amdgcn_s_setprio(0);                                            \
  }

template <int CSH, int KCONV, int KTOT, int MODE>
__global__ __launch_bounds__(256, 2) void fused_layer_kernel(
    const unsigned short* __restrict__ in, const short* __restrict__ woff,
    const float* __restrict__ offb,
    const short* __restrict__ wbf, const float* __restrict__ cbv,
    const unsigned short* __restrict__ xid, float* __restrict__ outf,
    unsigned short* __restrict__ outb) {
  __shared__ __align__(16) char smem[50176];
  uint4* dsu = (uint4*)smem;                    // [576] descriptors
  f32x4* redf = (f32x4*)smem;                   // [16*128] overlays dsu (post)
  float* offlds = (float*)(smem + 32768);       // [18*64] phase A -> B
  short* trans = (short*)(smem + 32768);        // 64 x 136 (epilogue, mode 0)

  const int tid = threadIdx.x;
  const int lane = tid & 63, wv = tid >> 6;
  const int pb = ((blockIdx.x & 7) << 6) | (blockIdx.x >> 3);  // XCD swizzle
  const int pix0 = pb << 6;
  const int x0 = pix0 & 127, y = (pix0 >> 7) & 127, b = pix0 >> 14;
  constexpr int Cin = 1 << CSH;
  const unsigned short* inb = in + (size_t)b * HWSZ * Cin;
  const int l15 = lane & 15, quad = lane >> 4;
  const int pxg = wv & 1, kh = wv >> 1;         // phase-C wave roles
  const int dp0 = pxg * 32 + (lane >> 2);
  const int dp1 = dp0 + 16;
  const int cq = lane & 3;
  const int baddr = (((lane & 15) << 2) | (lane >> 4)) << 2;  // bpermute src*4

  // ================= Phase A: offset conv (16 px x 32 M per wave) ========
  {
    constexpr int NCh = (9 << CSH) >> 5;        // 18 or 36
    const int pxa = wv;                          // wave = px group 0..3
    const int px = x0 + pxa * 16 + l15;
    f32x4 aco0 = {0.f, 0.f, 0.f, 0.f};
    f32x4 aco1 = {0.f, 0.f, 0.f, 0.f};
#pragma unroll
    for (int i = 0; i < NCh; i++) {
      int k0 = i * 32;
      int n = k0 >> CSH;
      int c0 = (k0 & (Cin - 1)) + quad * 8;
      int yy = y + n / 3 - 1;
      int xx = px + n % 3 - 1;
      bf16x8 bv = {};
      if (((unsigned)yy < (unsigned)HH) && ((unsigned)xx < (unsigned)WW))
        bv = *(const bf16x8*)&inb[((size_t)yy * WW + xx) * Cin + c0];
      int fbase = i * 1024 + lane * 8;
      bf16x8 a0 = *(const bf16x8*)&woff[fbase];
      bf16x8 a1 = *(const bf16x8*)&woff[fbase + 512];
      aco0 = __builtin_amdgcn_mfma_f32_16x16x32_bf16(a0, bv, aco0, 0, 0, 0);
      aco1 = __builtin_amdgcn_mfma_f32_16x16x32_bf16(a1, bv, aco1, 0, 0, 0);
    }
#pragma unroll
    for (int r = 0; r < 4; r++) {
      int o0 = quad * 4 + r;                     // 0..15: always valid
      offlds[o0 * 64 + pxa * 16 + l15] = aco0[r] + offb[o0];
      int o1 = 16 + quad * 4 + r;
      if (o1 < 18)
        offlds[o1 * 64 + pxa * 16 + l15] = aco1[r] + offb[o1];
    }
  }

  // pipeline register sets (named; no runtime-indexed arrays -> no scratch)
  bf16x8 Aw0, Aw1, Aw2, Aw3, Aw4, Aw5, Aw6, Aw7;
  bf16x8 Bw0, Bw1, Bw2, Bw3, Bw4, Bw5, Bw6, Bw7;
  uint4 Aq00, Aq01, Aq02, Aq03, Aq10, Aq11, Aq12, Aq13;
  uint4 Bq00, Bq01, Bq02, Bq03, Bq10, Bq11, Bq12, Bq13;
  unsigned Awa0, Awb0, Awa1, Awb1, Bwa0, Bwb0, Bwa1, Bwb1;
  uint4 Dd0, Dd1;                               // descriptor prefetch regs

  constexpr int NC = KTOT >> 5;
  constexpr int NCONV = KCONV >> 5;
  constexpr int HC = NC >> 1;
  const int kcBeg = kh * HC;
  const int kcEnd = kcBeg + HC;
  const int kcEndConv = (kcEnd < NCONV) ? kcEnd : NCONV;
  const short* wfb = wbf + lane * 8;

  LOADW(A, kcBeg);            // weights don't depend on descriptors
  __syncthreads();            // offlds complete

  // ================= Phase B: bilinear descriptors ========================
  for (int t = tid; t < 576; t += 256) {
    int n = t >> 6, pp = t & 63;
    float offy = offlds[n * 64 + pp];
    float offx = offlds[(9 + n) * 64 + pp];
    float py = offy + (float)(n / 3 - 1) + (float)(y + 1);
    float px = offx + (float)(n % 3 - 1) + (float)(x0 + pp + 1);
    py = fminf(fmaxf(py, 0.f), 129.f);
    px = fminf(fmaxf(px, 0.f), 129.f);
    float fy = floorf(py), fx = floorf(px);
    float qy1 = fminf(fy + 1.f, 129.f), qx1 = fminf(fx + 1.f, 129.f);
    float ty0 = 1.f + fy - py, ty1 = 1.f - (qy1 - py);
    float tx0 = 1.f + fx - px, tx1 = 1.f - (qx1 - px);
    int iy0 = (int)fy - 1, ix0 = (int)fx - 1;
    int iy1 = (int)qy1 - 1, ix1 = (int)qx1 - 1;
    if ((unsigned)iy0 >= (unsigned)HH) ty0 = 0.f;
    if ((unsigned)iy1 >= (unsigned)HH) ty1 = 0.f;
    if ((unsigned)ix0 >= (unsigned)WW) tx0 = 0.f;
    if ((unsigned)ix1 >= (unsigned)WW) tx1 = 0.f;
    int by0 = min(max(iy0, 0), HH - 1), by1 = min(max(iy1, 0), HH - 1);
    int bx0 = min(max(ix0, 0), WW - 1), bx1 = min(max(ix1, 0), WW - 1);
    uint4 d4;
    d4.x = (unsigned)(unsigned short)tobf(ty0 * tx0)
         | ((unsigned)(unsigned short)tobf(ty0 * tx1) << 16);
    d4.y = (unsigned)(unsigned short)tobf(ty1 * tx0)
         | ((unsigned)(unsigned short)tobf(ty1 * tx1) << 16);
    d4.z = (unsigned)((by0 * WW + bx0) * Cin);
    d4.w = (unsigned)((((by1 - by0) * WW * Cin) << 16) | ((bx1 - bx0) * Cin));
    dsu[t] = d4;
  }

  f32x4 acc[16];
#pragma unroll
  for (int j = 0; j < 16; j++) acc[j] = (f32x4){0.f, 0.f, 0.f, 0.f};

  __syncthreads();            // descriptors ready

  // ================= Phase C: pipelined deform GEMM =======================
  const int kcLast = kcEndConv - 1;
  LOADD(kcBeg);
  LOADG(A, kcBeg);
  LOADD(min(kcBeg + 1, kcLast));
  int i = kcBeg;
  for (; i + 2 <= kcEndConv; i += 2) {
    LOADW(B, i + 1);
    LOADG(B, i + 1);
    LOADD(min(i + 2, kcLast));
    COMPUTE(A);
    if (i + 2 < kcEndConv) {
      LOADW(A, i + 2);
      LOADG(A, i + 2);
      LOADD(min(i + 3, kcLast));
    }
    COMPUTE(B);
  }
  if (i < kcEndConv) {        // odd tail (A holds it)
    COMPUTE(A);
    i++;
  }

  // residual (identity) chunks: layer 2, kh=1 only
  if (KCONV < KTOT) {
    for (; i < kcEnd; i++) {
      LOADW(A, i);
      int c = ((i << 5) - KCONV) + cq * 8;
      uint4 pk0 = *(const uint4*)&xid[((size_t)(b * HWSZ) + y * WW + x0 + dp0) * 64 + c];
      uint4 pk1 = *(const uint4*)&xid[((size_t)(b * HWSZ) + y * WW + x0 + dp1) * 64 + c];
      bf16x8 bf0, bf1;
      XPOSE(pk0, bf0);
      XPOSE(pk1, bf1);
      __builtin_amdgcn_s_setprio(1);
      MFMA16(A, bf0, bf1);
      __builtin_amdgcn_s_setprio(0);
    }
  }

  // ---- K-half reduce (redf overlays dsu; both dead regions by now) ----
  __syncthreads();
  if (kh == 1) {
#pragma unroll
    for (int f = 0; f < 16; f++) redf[f * 128 + pxg * 64 + lane] = acc[f];
  }
  __syncthreads();
  if (kh == 0) {
#pragma unroll
    for (int f = 0; f < 16; f++) acc[f] += redf[f * 128 + pxg * 64 + lane];
    if (MODE == 1) {
#pragma unroll
      for (int f = 0; f < 16; f++) {
        int px_ = x0 + pxg * 32 + (f >> 3) * 16 + l15;
        int fo = f & 7;
#pragma unroll
        for (int r = 0; r < 4; r++) {
          int o = (fo >> 2) * 64 + (fo & 3) * 16 + quad * 4 + r;
          outf[(size_t)(b * COUT + o) * HWSZ + y * WW + px_] =
              fmaxf(acc[f][r] + cbv[o], 0.f);
        }
      }
    } else {
#pragma unroll
      for (int f = 0; f < 16; f++) {
        int pl = pxg * 32 + (f >> 3) * 16 + l15;
        int fo = f & 7;
        s16x4 t4;
#pragma unroll
        for (int r = 0; r < 4; r++) {
          int o = (fo >> 2) * 64 + (fo & 3) * 16 + quad * 4 + r;
          t4[r] = tobf(fmaxf(acc[f][r] + cbv[o], 0.f));
        }
        *(s16x4*)&trans[pl * 136 + (fo >> 2) * 64 + (fo & 3) * 16 + quad * 4] = t4;
      }
    }
  }
  if (MODE == 0) {
    __syncthreads();
    int pw = tid >> 2, cs = (tid & 3) * 32;
    size_t gb = ((size_t)(b * HWSZ) + y * WW + x0 + pw) * 128 + cs;
#pragma unroll
    for (int s = 0; s < 4; s++) {
      u16x8 v8 = *(const u16x8*)&trans[pw * 136 + cs + s * 8];
      *(u16x8*)&outb[gb + s * 8] = v8;
    }
  }
}

// ---------------------------------------------------------------------------
extern "C" void kernel_launch(void* const* d_in, const int* in_sizes, int n_in,
                              void* d_out, int out_size, void* d_ws, size_t ws_size,
                              hipStream_t stream) {
  const float* x        = (const float*)d_in[0];
  const float* dc1_offw = (const float*)d_in[1];
  const float* dc1_offb = (const float*)d_in[2];
  const float* dc1_w    = (const float*)d_in[3];
  const float* bn1_g    = (const float*)d_in[4];
  const float* bn1_b    = (const float*)d_in[5];
  const float* bn1_m    = (const float*)d_in[6];
  const float* bn1_v    = (const float*)d_in[7];
  const float* dc2_offw = (const float*)d_in[8];
  const float* dc2_offb = (const float*)d_in[9];
  const float* dc2_w    = (const float*)d_in[10];
  const float* bn2_g    = (const float*)d_in[11];
  const float* bn2_b    = (const float*)d_in[12];
  const float* bn2_m    = (const float*)d_in[13];
  const float* bn2_v    = (const float*)d_in[14];
  const float* id_w     = (const float*)d_in[15];
  const float* id_b     = (const float*)d_in[16];
  const float* bn3_g    = (const float*)d_in[17];
  const float* bn3_b    = (const float*)d_in[18];
  const float* bn3_m    = (const float*)d_in[19];
  const float* bn3_v    = (const float*)d_in[20];

  float* wsf = (float*)d_ws;
  float* cb1  = wsf;
  float* cb2  = cb1 + 128;
  unsigned short* xbf = (unsigned short*)(cb2 + 128);  // NHWC (B,H,W,64)
  unsigned short* h1  = xbf + (size_t)BB * HWSZ * 64;  // NHWC (B,H,W,128)
  short* wbf1  = (short*)(h1 + (size_t)BB * HWSZ * COUT);  // frag 128x576
  short* wbf2  = wbf1 + (size_t)128 * 576;             // frag 128x1216
  short* woff1 = wbf2 + (size_t)128 * 1216;            // frag-order 18*1024
  short* woff2 = woff1 + (size_t)18 * 1024;            // frag-order 36*1024

  hipLaunchKernelGGL(prep_all_kernel, dim3((PA5 + 255) / 256), dim3(256), 0, stream,
                     dc1_w, dc2_w, id_w, dc1_offw, dc2_offw,
                     bn1_g, bn1_b, bn1_m, bn1_v, bn2_g, bn2_b, bn2_m, bn2_v,
                     bn3_g, bn3_b, bn3_m, bn3_v, id_b,
                     wbf1, wbf2, woff1, woff2, cb1, cb2);
  hipLaunchKernelGGL(xcast_kernel, dim3(BB * HWSZ / 64), dim3(256), 0, stream, x, xbf);

  // --- layer 1 (offset conv fused) ---
  hipLaunchKernelGGL((fused_layer_kernel<6, 576, 576, 0>), dim3(512), dim3(256), 0, stream,
                     xbf, woff1, dc1_offb, wbf1, cb1,
                     (const unsigned short*)nullptr, (float*)nullptr, h1);
  // --- layer 2 (offset conv + identity residual fused) ---
  hipLaunchKernelGGL((fused_layer_kernel<7, 1152, 1216, 1>), dim3(512), dim3(256), 0, stream,
                     h1, woff2, dc2_offb, wbf2, cb2,
                     xbf, (float*)d_out, (unsigned short*)nullptr);
}